// Round 1
// baseline (377.912 us; speedup 1.0000x reference)
//
#include <hip/hip_runtime.h>
#include <math.h>

#define D_MODEL 512
#define NTOK 2048
#define QGRP 4
#define NHEAD 8
#define HDIM 64
#define ROWS_PER_T (QGRP * NTOK)          /* 8192 */
#define TOTAL_LN_ROWS (3 * ROWS_PER_T)    /* 24576 */
#define LN_EPS 1e-5f

/* ---------------- Kernel 1: LayerNorm row stats (mu, rstd) ---------------- */
__global__ __launch_bounds__(256)
void ln_stats_kernel(const float* __restrict__ q, const float* __restrict__ k,
                     const float* __restrict__ v,
                     float* __restrict__ mu, float* __restrict__ rstd) {
    int wave = threadIdx.x >> 6;
    int lane = threadIdx.x & 63;
    long row = (long)blockIdx.x * 4 + wave;
    if (row >= TOTAL_LN_ROWS) return;
    int t = (int)(row / ROWS_PER_T);
    long r = row % ROWS_PER_T;
    const float* src = (t == 0 ? q : (t == 1 ? k : v)) + r * D_MODEL;
    float4 a = *(const float4*)(src + lane * 8);
    float4 b = *(const float4*)(src + lane * 8 + 4);
    float s  = a.x + a.y + a.z + a.w + b.x + b.y + b.z + b.w;
    float sq = a.x*a.x + a.y*a.y + a.z*a.z + a.w*a.w
             + b.x*b.x + b.y*b.y + b.z*b.z + b.w*b.w;
    for (int m = 1; m < 64; m <<= 1) {
        s  += __shfl_xor(s, m);
        sq += __shfl_xor(sq, m);
    }
    if (lane == 0) {
        float m_  = s * (1.0f / (float)D_MODEL);
        float var = sq * (1.0f / (float)D_MODEL) - m_ * m_;
        mu[row]   = m_;
        rstd[row] = 1.0f / sqrtf(var + LN_EPS);
    }
}

/* ------------- Kernel 2: fused LN-apply + GEMM  f = LN(x) @ w_in^T ------------- */
/* A' rows 64 x cols(K) 32 tile; W rows 64 x 32; 256 thr, 4x4 per thread */
__global__ __launch_bounds__(256)
void ln_gemm_kernel(const float* __restrict__ qp, const float* __restrict__ kp,
                    const float* __restrict__ vp, const float* __restrict__ W,
                    const float* __restrict__ gamma, const float* __restrict__ beta,
                    const float* __restrict__ mu, const float* __restrict__ rstd,
                    float* __restrict__ fout) {
    __shared__ float As[32][68];
    __shared__ float Ws[32][68];
    int t = blockIdx.z;
    const float* A = (t == 0 ? qp : (t == 1 ? kp : vp));
    float* C = fout + (size_t)t * ROWS_PER_T * D_MODEL;
    const float* mu_t = mu + (size_t)t * ROWS_PER_T;
    const float* rs_t = rstd + (size_t)t * ROWS_PER_T;
    int tid = threadIdx.x;
    int tx = tid & 15, ty = tid >> 4;
    size_t rowBase = (size_t)blockIdx.x * 64;
    int colBase = blockIdx.y * 64;
    float acc[4][4] = {{0.f}};
    for (int kt = 0; kt < D_MODEL; kt += 32) {
#pragma unroll
        for (int it = 0; it < 2; ++it) {
            int t2 = tid + it * 256;
            int r  = t2 >> 3;
            int kk = (t2 & 7) << 2;
            size_t gr = rowBase + r;
            float4 va = *(const float4*)(A + gr * D_MODEL + kt + kk);
            float m_ = mu_t[gr], rs = rs_t[gr];
            As[kk+0][r] = (va.x - m_) * rs * gamma[kt+kk+0] + beta[kt+kk+0];
            As[kk+1][r] = (va.y - m_) * rs * gamma[kt+kk+1] + beta[kt+kk+1];
            As[kk+2][r] = (va.z - m_) * rs * gamma[kt+kk+2] + beta[kt+kk+2];
            As[kk+3][r] = (va.w - m_) * rs * gamma[kt+kk+3] + beta[kt+kk+3];
            float4 vw = *(const float4*)(W + (size_t)(colBase + r) * D_MODEL + kt + kk);
            Ws[kk+0][r] = vw.x; Ws[kk+1][r] = vw.y;
            Ws[kk+2][r] = vw.z; Ws[kk+3][r] = vw.w;
        }
        __syncthreads();
#pragma unroll
        for (int kk2 = 0; kk2 < 32; ++kk2) {
            float4 a4 = *(const float4*)&As[kk2][ty << 2];
            float4 b4 = *(const float4*)&Ws[kk2][tx << 2];
            acc[0][0] += a4.x*b4.x; acc[0][1] += a4.x*b4.y; acc[0][2] += a4.x*b4.z; acc[0][3] += a4.x*b4.w;
            acc[1][0] += a4.y*b4.x; acc[1][1] += a4.y*b4.y; acc[1][2] += a4.y*b4.z; acc[1][3] += a4.y*b4.w;
            acc[2][0] += a4.z*b4.x; acc[2][1] += a4.z*b4.y; acc[2][2] += a4.z*b4.z; acc[2][3] += a4.z*b4.w;
            acc[3][0] += a4.w*b4.x; acc[3][1] += a4.w*b4.y; acc[3][2] += a4.w*b4.z; acc[3][3] += a4.w*b4.w;
        }
        __syncthreads();
    }
#pragma unroll
    for (int i = 0; i < 4; ++i) {
        float4 o;
        o.x = acc[i][0]; o.y = acc[i][1]; o.z = acc[i][2]; o.w = acc[i][3];
        *(float4*)(C + (rowBase + (ty << 2) + i) * D_MODEL + colBase + (tx << 2)) = o;
    }
}

/* ------- Kernel 3: per-(head,group) K-side reductions (partials, no atomics) -------
   P  = Fk^T diag(1/|fk|) Fv   [64x64]
   Cv = Fk^T Fv                [64x64]
   u  = Fv^T kvar              [64]                                                */
__global__ __launch_bounds__(256)
void pair_reduce_kernel(const float* __restrict__ f, float* __restrict__ partials) {
    int pc = blockIdx.x;              /* pair*8 + chunk */
    int pair = pc >> 3, chunk = pc & 7;
    int h = pair & 7, qg = pair >> 3;
    const float* Fk = f + ((size_t)(ROWS_PER_T     + qg * NTOK)) * D_MODEL + h * HDIM;
    const float* Fv = f + ((size_t)(2 * ROWS_PER_T + qg * NTOK)) * D_MODEL + h * HDIM;
    __shared__ float fk_s[64][64];
    __shared__ float fv_s[64][64];
    __shared__ float rkn_s[64], kvar_s[64];
    int tid = threadIdx.x;
    int a0 = (tid >> 4) << 2, b0 = (tid & 15) << 2;
    int lr = tid >> 4;
    int lc = (tid & 15) << 2;
    float accP[4][4] = {{0.f}}, accC[4][4] = {{0.f}};
    float uv[4] = {0.f, 0.f, 0.f, 0.f};
    for (int t = 0; t < 4; ++t) {
        int rowbase = chunk * 256 + t * 64;
        float4 vk[4], vv[4];
#pragma unroll
        for (int j = 0; j < 4; ++j) {
            size_t n = (size_t)(rowbase + lr + 16 * j);
            vk[j] = *(const float4*)(Fk + n * D_MODEL + lc);
            vv[j] = *(const float4*)(Fv + n * D_MODEL + lc);
        }
        __syncthreads();   /* previous compute done before overwriting LDS */
#pragma unroll
        for (int j = 0; j < 4; ++j) {
            int m = lr + 16 * j;
            *(float4*)&fk_s[m][lc] = vk[j];
            *(float4*)&fv_s[m][lc] = vv[j];
        }
        /* stats: 16-lane-group reduce over each row of Fk */
#pragma unroll
        for (int j = 0; j < 4; ++j) {
            float s  = vk[j].x + vk[j].y + vk[j].z + vk[j].w;
            float sq = vk[j].x*vk[j].x + vk[j].y*vk[j].y + vk[j].z*vk[j].z + vk[j].w*vk[j].w;
            for (int msk = 1; msk < 16; msk <<= 1) {
                s  += __shfl_xor(s,  msk);
                sq += __shfl_xor(sq, msk);
            }
            if ((tid & 15) == 0) {
                int m = lr + 16 * j;
                rkn_s[m]  = 1.0f / sqrtf(sq);
                kvar_s[m] = (sq - s * s * (1.0f / 64.0f)) * (1.0f / 63.0f);
            }
        }
        __syncthreads();
#pragma unroll
        for (int m = 0; m < 64; ++m) {
            float4 fk4 = *(const float4*)&fk_s[m][a0];
            float4 fv4 = *(const float4*)&fv_s[m][b0];
            float rkn = rkn_s[m];
            float fkn[4] = {fk4.x*rkn, fk4.y*rkn, fk4.z*rkn, fk4.w*rkn};
            float fkr[4] = {fk4.x, fk4.y, fk4.z, fk4.w};
            float fvr[4] = {fv4.x, fv4.y, fv4.z, fv4.w};
#pragma unroll
            for (int i = 0; i < 4; ++i)
#pragma unroll
                for (int jj = 0; jj < 4; ++jj) {
                    accP[i][jj] += fkn[i] * fvr[jj];
                    accC[i][jj] += fkr[i] * fvr[jj];
                }
            if ((tid >> 4) == 0) {
                float kv = kvar_s[m];
#pragma unroll
                for (int jj = 0; jj < 4; ++jj) uv[jj] += kv * fvr[jj];
            }
        }
    }
    float* outp = partials + (size_t)pc * 8256;
#pragma unroll
    for (int i = 0; i < 4; ++i) {
        float4 o1, o2;
        o1.x = accP[i][0]; o1.y = accP[i][1]; o1.z = accP[i][2]; o1.w = accP[i][3];
        o2.x = accC[i][0]; o2.y = accC[i][1]; o2.z = accC[i][2]; o2.w = accC[i][3];
        *(float4*)(outp + (a0 + i) * 64 + b0)        = o1;
        *(float4*)(outp + 4096 + (a0 + i) * 64 + b0) = o2;
    }
    if ((tid >> 4) == 0) {
        float4 o;
        o.x = uv[0]; o.y = uv[1]; o.z = uv[2]; o.w = uv[3];
        *(float4*)(outp + 8192 + b0) = o;
    }
}

/* -------- Kernel 3b: reduce 8 partials per pair; also column sums of Cv -------- */
__global__ __launch_bounds__(256)
void pair_finalize_kernel(const float* __restrict__ partials, float* __restrict__ pairacc) {
    int pair = blockIdx.x;
    __shared__ float buf[8256];
    for (int e = threadIdx.x; e < 8256; e += 256) {
        float s = 0.f;
        for (int c = 0; c < 8; ++c)
            s += partials[((size_t)(pair * 8 + c)) * 8256 + e];
        buf[e] = s;
        pairacc[(size_t)pair * 8320 + e] = s;
    }
    __syncthreads();
    if (threadIdx.x < 64) {
        float s = 0.f;
        for (int a = 0; a < 64; ++a) s += buf[4096 + a * 64 + threadIdx.x];
        pairacc[(size_t)pair * 8320 + 8256 + threadIdx.x] = s;
    }
}

/* -------- Kernel 4: Q-side row stats + two 64x64 matvecs + combine -------- */
__global__ __launch_bounds__(256)
void q_apply_kernel(const float* __restrict__ f, const float* __restrict__ pairacc,
                    const float* __restrict__ cov_raw, const float* __restrict__ var_raw,
                    float* __restrict__ attnout) {
    int bid = blockIdx.x;             /* pair*64 + nchunk */
    int pair = bid >> 6, nchunk = bid & 63;
    int h = pair & 7, qg = pair >> 3;
    __shared__ float P_s[4096];
    __shared__ float C_s[4096];
    __shared__ float u_s[64], sc_s[64];
    const float* pa = pairacc + (size_t)pair * 8320;
    for (int e = threadIdx.x; e < 4096; e += 256) {
        P_s[e] = pa[e];
        C_s[e] = pa[4096 + e];
    }
    if (threadIdx.x < 64) {
        u_s[threadIdx.x]  = pa[8192 + threadIdx.x];
        sc_s[threadIdx.x] = pa[8256 + threadIdx.x];
    }
    __syncthreads();
    float cov_w = 1.0f / (1.0f + expf(-cov_raw[0]));
    float var_w = 1.0f / (1.0f + expf(-var_raw[0]));
    float cos_w = 1.0f - cov_w - var_w;
    float cw_cov = cov_w * (1.0f / 64.0f);
    float cw_var = var_w * (1.0f / 64.0f);
    int wave = threadIdx.x >> 6, lane = threadIdx.x & 63;
    const float* Fq = f + ((size_t)(qg * NTOK)) * D_MODEL + h * HDIM;
    for (int r = 0; r < 8; ++r) {
        int n = nchunk * 32 + wave * 8 + r;
        float fq = Fq[(size_t)n * D_MODEL + lane];
        float s = fq, sq = fq * fq;
        for (int m = 1; m < 64; m <<= 1) {
            s  += __shfl_xor(s, m);
            sq += __shfl_xor(sq, m);
        }
        float qmean = s * (1.0f / 64.0f);
        float rqn   = 1.0f / sqrtf(sq);
        float qvar  = (sq - s * qmean) * (1.0f / 63.0f);
        float y1 = 0.f, y2 = 0.f;
#pragma unroll 8
        for (int a = 0; a < 64; ++a) {
            float vbc = __shfl(fq, a);
            y1 += vbc * P_s[a * 64 + lane];
            y2 += vbc * C_s[a * 64 + lane];
        }
        float res = cos_w * rqn * y1
                  + cw_cov * (y2 - qmean * sc_s[lane])
                  + cw_var * qvar * u_s[lane];
        attnout[((size_t)(qg * NTOK + n)) * D_MODEL + h * HDIM + lane] = res;
    }
}

/* ------------- Kernel 5: out = attnout @ w_out^T + b_out ------------- */
__global__ __launch_bounds__(256)
void out_gemm_kernel(const float* __restrict__ A, const float* __restrict__ W,
                     const float* __restrict__ bias, float* __restrict__ C) {
    __shared__ float As[32][68];
    __shared__ float Ws[32][68];
    int tid = threadIdx.x;
    int tx = tid & 15, ty = tid >> 4;
    size_t rowBase = (size_t)blockIdx.x * 64;
    int colBase = blockIdx.y * 64;
    float acc[4][4] = {{0.f}};
    for (int kt = 0; kt < D_MODEL; kt += 32) {
#pragma unroll
        for (int it = 0; it < 2; ++it) {
            int t2 = tid + it * 256;
            int r  = t2 >> 3;
            int kk = (t2 & 7) << 2;
            size_t gr = rowBase + r;
            float4 va = *(const float4*)(A + gr * D_MODEL + kt + kk);
            As[kk+0][r] = va.x; As[kk+1][r] = va.y;
            As[kk+2][r] = va.z; As[kk+3][r] = va.w;
            float4 vw = *(const float4*)(W + (size_t)(colBase + r) * D_MODEL + kt + kk);
            Ws[kk+0][r] = vw.x; Ws[kk+1][r] = vw.y;
            Ws[kk+2][r] = vw.z; Ws[kk+3][r] = vw.w;
        }
        __syncthreads();
#pragma unroll
        for (int kk2 = 0; kk2 < 32; ++kk2) {
            float4 a4 = *(const float4*)&As[kk2][ty << 2];
            float4 b4 = *(const float4*)&Ws[kk2][tx << 2];
            acc[0][0] += a4.x*b4.x; acc[0][1] += a4.x*b4.y; acc[0][2] += a4.x*b4.z; acc[0][3] += a4.x*b4.w;
            acc[1][0] += a4.y*b4.x; acc[1][1] += a4.y*b4.y; acc[1][2] += a4.y*b4.z; acc[1][3] += a4.y*b4.w;
            acc[2][0] += a4.z*b4.x; acc[2][1] += a4.z*b4.y; acc[2][2] += a4.z*b4.z; acc[2][3] += a4.z*b4.w;
            acc[3][0] += a4.w*b4.x; acc[3][1] += a4.w*b4.y; acc[3][2] += a4.w*b4.z; acc[3][3] += a4.w*b4.w;
        }
        __syncthreads();
    }
#pragma unroll
    for (int i = 0; i < 4; ++i) {
        int col = colBase + (tx << 2);
        float4 o;
        o.x = acc[i][0] + bias[col+0];
        o.y = acc[i][1] + bias[col+1];
        o.z = acc[i][2] + bias[col+2];
        o.w = acc[i][3] + bias[col+3];
        *(float4*)(C + (rowBase + (ty << 2) + i) * D_MODEL + col) = o;
    }
}

extern "C" void kernel_launch(void* const* d_in, const int* in_sizes, int n_in,
                              void* d_out, int out_size, void* d_ws, size_t ws_size,
                              hipStream_t stream) {
    const float* q     = (const float*)d_in[0];
    const float* k     = (const float*)d_in[1];
    const float* v     = (const float*)d_in[2];
    const float* gamma = (const float*)d_in[3];
    const float* beta  = (const float*)d_in[4];
    const float* w_in  = (const float*)d_in[5];
    const float* w_out = (const float*)d_in[6];
    const float* b_out = (const float*)d_in[7];
    const float* cov_r = (const float*)d_in[8];
    const float* var_r = (const float*)d_in[9];
    float* out = (float*)d_out;

    float* ws       = (float*)d_ws;
    float* mu       = ws;                                   /* 24576 */
    float* rstd     = ws + 24576;                           /* 24576 */
    float* f        = ws + 49152;                           /* 3*8192*512 */
    float* partials = f + (size_t)3 * ROWS_PER_T * D_MODEL; /* 256*8256 */
    float* pairacc  = partials + (size_t)256 * 8256;        /* 32*8320 */
    float* attnout  = pairacc + (size_t)32 * 8320;          /* 8192*512 */

    hipLaunchKernelGGL(ln_stats_kernel, dim3(TOTAL_LN_ROWS / 4), dim3(256), 0, stream,
                       q, k, v, mu, rstd);
    hipLaunchKernelGGL(ln_gemm_kernel, dim3(ROWS_PER_T / 64, D_MODEL / 64, 3), dim3(256), 0, stream,
                       q, k, v, w_in, gamma, beta, mu, rstd, f);
    hipLaunchKernelGGL(pair_reduce_kernel, dim3(256), dim3(256), 0, stream, f, partials);
    hipLaunchKernelGGL(pair_finalize_kernel, dim3(32), dim3(256), 0, stream, partials, pairacc);
    hipLaunchKernelGGL(q_apply_kernel, dim3(2048), dim3(256), 0, stream,
                       f, pairacc, cov_r, var_r, attnout);
    hipLaunchKernelGGL(out_gemm_kernel, dim3(ROWS_PER_T / 64, D_MODEL / 64), dim3(256), 0, stream,
                       attnout, w_out, b_out, out);
}

// Round 2
// 247.983 us; speedup vs baseline: 1.5239x; 1.5239x over previous
//
#include <hip/hip_runtime.h>
#include <hip/hip_bf16.h>
#include <math.h>

#define D_MODEL 512
#define NTOK 2048
#define QGRP 4
#define NHEAD 8
#define HDIM 64
#define ROWS_PER_T (QGRP * NTOK)          /* 8192 */
#define LN_EPS 1e-5f

typedef __attribute__((ext_vector_type(8))) short short8;
typedef __attribute__((ext_vector_type(8))) __bf16 bf16x8;
typedef __attribute__((ext_vector_type(4))) float f32x4;

__device__ inline void split2(float y, ushort& h, ushort& l) {
    __hip_bfloat16 hb = __float2bfloat16(y);
    float hf = __bfloat162float(hb);
    __hip_bfloat16 lb = __float2bfloat16(y - hf);
    h = *reinterpret_cast<ushort*>(&hb);
    l = *reinterpret_cast<ushort*>(&lb);
}

/* ------- Kernel 1: fused LayerNorm + bf16 hi/lo split:  A = LN(x)*gamma+beta ------- */
__global__ __launch_bounds__(256)
void ln_split_kernel(const float* __restrict__ x, const float* __restrict__ gamma,
                     const float* __restrict__ beta,
                     ushort* __restrict__ Ah, ushort* __restrict__ Al) {
    int wave = threadIdx.x >> 6, lane = threadIdx.x & 63;
    size_t row = (size_t)blockIdx.x * 4 + wave;
    const float* src = x + row * D_MODEL + lane * 8;
    float4 a = *(const float4*)src;
    float4 b = *(const float4*)(src + 4);
    float s  = a.x + a.y + a.z + a.w + b.x + b.y + b.z + b.w;
    float sq = a.x*a.x + a.y*a.y + a.z*a.z + a.w*a.w
             + b.x*b.x + b.y*b.y + b.z*b.z + b.w*b.w;
    for (int m = 1; m < 64; m <<= 1) {
        s  += __shfl_xor(s, m);
        sq += __shfl_xor(sq, m);
    }
    float mu   = s * (1.0f / (float)D_MODEL);
    float var  = sq * (1.0f / (float)D_MODEL) - mu * mu;
    float rstd = 1.0f / sqrtf(var + LN_EPS);
    float4 g0 = *(const float4*)(gamma + lane * 8);
    float4 g1 = *(const float4*)(gamma + lane * 8 + 4);
    float4 t0 = *(const float4*)(beta + lane * 8);
    float4 t1 = *(const float4*)(beta + lane * 8 + 4);
    float xv[8] = {a.x, a.y, a.z, a.w, b.x, b.y, b.z, b.w};
    float gv[8] = {g0.x, g0.y, g0.z, g0.w, g1.x, g1.y, g1.z, g1.w};
    float bv[8] = {t0.x, t0.y, t0.z, t0.w, t1.x, t1.y, t1.z, t1.w};
    ushort hs[8], ls[8];
#pragma unroll
    for (int j = 0; j < 8; ++j) {
        float y = (xv[j] - mu) * rstd * gv[j] + bv[j];
        split2(y, hs[j], ls[j]);
    }
    *(short8*)(Ah + row * D_MODEL + lane * 8) = *(const short8*)hs;
    *(short8*)(Al + row * D_MODEL + lane * 8) = *(const short8*)ls;
}

/* ------- Kernel 2: plain elementwise hi/lo split (for weights) ------- */
__global__ __launch_bounds__(256)
void split_mat_kernel(const float* __restrict__ W, ushort* __restrict__ Wh,
                      ushort* __restrict__ Wl) {
    size_t i = ((size_t)blockIdx.x * 256 + threadIdx.x) * 8;
    float4 a = *(const float4*)(W + i);
    float4 b = *(const float4*)(W + i + 4);
    float xv[8] = {a.x, a.y, a.z, a.w, b.x, b.y, b.z, b.w};
    ushort hs[8], ls[8];
#pragma unroll
    for (int j = 0; j < 8; ++j) split2(xv[j], hs[j], ls[j]);
    *(short8*)(Wh + i) = *(const short8*)hs;
    *(short8*)(Wl + i) = *(const short8*)ls;
}

/* ------- Kernel 3: split-bf16 MFMA GEMM  C[M,512] = (Ah+Al)(Wh+Wl)^T (+bias) -------
   128x128 tile, BK=64, 4 waves (2x2), 16x16x32 MFMA, 3 products (hh, hl, lh).
   LDS tiles XOR-swizzled in 8-elem granules: col_granule ^= (row & 7).            */
template <bool BIAS>
__global__ __launch_bounds__(256, 2)
void gemm_split_kernel(const ushort* __restrict__ Ah, const ushort* __restrict__ Al,
                       const ushort* __restrict__ Wh, const ushort* __restrict__ Wl,
                       const float* __restrict__ bias, float* __restrict__ C) {
    __shared__ __align__(16) ushort sA[2][128][64];
    __shared__ __align__(16) ushort sW[2][128][64];
    int tid  = threadIdx.x;
    int lane = tid & 63, wid = tid >> 6;
    int wr = wid >> 1, wc = wid & 1;
    size_t rowBase = (size_t)blockIdx.x * 128;
    size_t colBase = (size_t)blockIdx.y * 128;
    const ushort* gA[2] = {Ah, Al};
    const ushort* gW[2] = {Wh, Wl};

    int sr = tid >> 3;            /* staging row stepped by 32 per pass   */
    int sc8 = tid & 7;            /* staging 8-elem column granule        */

    short8 st[16];

#define LOADK(KT)                                                                  \
    {                                                                              \
        int idx = 0;                                                               \
        _Pragma("unroll")                                                          \
        for (int hl = 0; hl < 2; ++hl)                                             \
            _Pragma("unroll")                                                      \
            for (int p = 0; p < 4; ++p) {                                          \
                int r = p * 32 + sr;                                               \
                st[idx++] = *(const short8*)(gA[hl] + (rowBase + r) * D_MODEL +    \
                                             (KT) + sc8 * 8);                      \
            }                                                                      \
        _Pragma("unroll")                                                          \
        for (int hl = 0; hl < 2; ++hl)                                             \
            _Pragma("unroll")                                                      \
            for (int p = 0; p < 4; ++p) {                                          \
                int r = p * 32 + sr;                                               \
                st[idx++] = *(const short8*)(gW[hl] + (colBase + r) * D_MODEL +    \
                                             (KT) + sc8 * 8);                      \
            }                                                                      \
    }

    f32x4 acc[4][4] = {};

    LOADK(0);
    for (int step = 0; step < 8; ++step) {
        __syncthreads();
        {   /* write staged regs to LDS, swizzled */
            int idx = 0;
#pragma unroll
            for (int hl = 0; hl < 2; ++hl)
#pragma unroll
                for (int p = 0; p < 4; ++p) {
                    int r = p * 32 + sr;
                    *(short8*)&sA[hl][r][((sc8 ^ (r & 7)) << 3)] = st[idx++];
                }
#pragma unroll
            for (int hl = 0; hl < 2; ++hl)
#pragma unroll
                for (int p = 0; p < 4; ++p) {
                    int r = p * 32 + sr;
                    *(short8*)&sW[hl][r][((sc8 ^ (r & 7)) << 3)] = st[idx++];
                }
        }
        __syncthreads();
        if (step < 7) LOADK((step + 1) * 64);
#pragma unroll
        for (int sl = 0; sl < 2; ++sl) {
            bf16x8 aH[4], aL[4];
#pragma unroll
            for (int m = 0; m < 4; ++m) {
                int r = wr * 64 + m * 16 + (lane & 15);
                int cs = ((sl * 4 + (lane >> 4)) ^ (r & 7)) << 3;
                aH[m] = *(const bf16x8*)&sA[0][r][cs];
                aL[m] = *(const bf16x8*)&sA[1][r][cs];
            }
#pragma unroll
            for (int n = 0; n < 4; ++n) {
                int r = wc * 64 + n * 16 + (lane & 15);
                int cs = ((sl * 4 + (lane >> 4)) ^ (r & 7)) << 3;
                bf16x8 bH = *(const bf16x8*)&sW[0][r][cs];
                bf16x8 bL = *(const bf16x8*)&sW[1][r][cs];
#pragma unroll
                for (int m = 0; m < 4; ++m) {
                    acc[m][n] = __builtin_amdgcn_mfma_f32_16x16x32_bf16(aL[m], bH, acc[m][n], 0, 0, 0);
                    acc[m][n] = __builtin_amdgcn_mfma_f32_16x16x32_bf16(aH[m], bL, acc[m][n], 0, 0, 0);
                    acc[m][n] = __builtin_amdgcn_mfma_f32_16x16x32_bf16(aH[m], bH, acc[m][n], 0, 0, 0);
                }
            }
        }
    }
#pragma unroll
    for (int m = 0; m < 4; ++m)
#pragma unroll
        for (int n = 0; n < 4; ++n) {
            size_t col = colBase + wc * 64 + n * 16 + (lane & 15);
            size_t rb  = rowBase + wr * 64 + m * 16 + ((lane >> 4) << 2);
            float bv = BIAS ? bias[col] : 0.0f;
#pragma unroll
            for (int r = 0; r < 4; ++r)
                C[(rb + r) * D_MODEL + col] = acc[m][n][r] + bv;
        }
#undef LOADK
}

/* ------- Kernel 4: per-(head,group) K-side reductions (4 chunks, no atomics) ------- */
__global__ __launch_bounds__(256)
void pair_reduce_kernel(const float* __restrict__ f, float* __restrict__ partials) {
    int pc = blockIdx.x;              /* pair*4 + chunk */
    int pair = pc >> 2, chunk = pc & 3;
    int h = pair & 7, qg = pair >> 3;
    const float* Fk = f + ((size_t)(ROWS_PER_T     + qg * NTOK)) * D_MODEL + h * HDIM;
    const float* Fv = f + ((size_t)(2 * ROWS_PER_T + qg * NTOK)) * D_MODEL + h * HDIM;
    __shared__ float fk_s[64][64];
    __shared__ float fv_s[64][64];
    __shared__ float rkn_s[64], kvar_s[64];
    int tid = threadIdx.x;
    int a0 = (tid >> 4) << 2, b0 = (tid & 15) << 2;
    int lr = tid >> 4;
    int lc = (tid & 15) << 2;
    float accP[4][4] = {{0.f}}, accC[4][4] = {{0.f}};
    float uv[4] = {0.f, 0.f, 0.f, 0.f};
    for (int t = 0; t < 8; ++t) {
        int rowbase = chunk * 512 + t * 64;
        float4 vk[4], vv[4];
#pragma unroll
        for (int j = 0; j < 4; ++j) {
            size_t n = (size_t)(rowbase + lr + 16 * j);
            vk[j] = *(const float4*)(Fk + n * D_MODEL + lc);
            vv[j] = *(const float4*)(Fv + n * D_MODEL + lc);
        }
        __syncthreads();
#pragma unroll
        for (int j = 0; j < 4; ++j) {
            int m = lr + 16 * j;
            *(float4*)&fk_s[m][lc] = vk[j];
            *(float4*)&fv_s[m][lc] = vv[j];
        }
#pragma unroll
        for (int j = 0; j < 4; ++j) {
            float s  = vk[j].x + vk[j].y + vk[j].z + vk[j].w;
            float sq = vk[j].x*vk[j].x + vk[j].y*vk[j].y + vk[j].z*vk[j].z + vk[j].w*vk[j].w;
            for (int msk = 1; msk < 16; msk <<= 1) {
                s  += __shfl_xor(s,  msk);
                sq += __shfl_xor(sq, msk);
            }
            if ((tid & 15) == 0) {
                int m = lr + 16 * j;
                rkn_s[m]  = 1.0f / sqrtf(sq);
                kvar_s[m] = (sq - s * s * (1.0f / 64.0f)) * (1.0f / 63.0f);
            }
        }
        __syncthreads();
#pragma unroll
        for (int m = 0; m < 64; ++m) {
            float4 fk4 = *(const float4*)&fk_s[m][a0];
            float4 fv4 = *(const float4*)&fv_s[m][b0];
            float rkn = rkn_s[m];
            float fkn[4] = {fk4.x*rkn, fk4.y*rkn, fk4.z*rkn, fk4.w*rkn};
            float fkr[4] = {fk4.x, fk4.y, fk4.z, fk4.w};
            float fvr[4] = {fv4.x, fv4.y, fv4.z, fv4.w};
#pragma unroll
            for (int i = 0; i < 4; ++i)
#pragma unroll
                for (int jj = 0; jj < 4; ++jj) {
                    accP[i][jj] += fkn[i] * fvr[jj];
                    accC[i][jj] += fkr[i] * fvr[jj];
                }
            if ((tid >> 4) == 0) {
                float kv = kvar_s[m];
#pragma unroll
                for (int jj = 0; jj < 4; ++jj) uv[jj] += kv * fvr[jj];
            }
        }
    }
    float* outp = partials + (size_t)pc * 8256;
#pragma unroll
    for (int i = 0; i < 4; ++i) {
        float4 o1, o2;
        o1.x = accP[i][0]; o1.y = accP[i][1]; o1.z = accP[i][2]; o1.w = accP[i][3];
        o2.x = accC[i][0]; o2.y = accC[i][1]; o2.z = accC[i][2]; o2.w = accC[i][3];
        *(float4*)(outp + (a0 + i) * 64 + b0)        = o1;
        *(float4*)(outp + 4096 + (a0 + i) * 64 + b0) = o2;
    }
    if ((tid >> 4) == 0) {
        float4 o;
        o.x = uv[0]; o.y = uv[1]; o.z = uv[2]; o.w = uv[3];
        *(float4*)(outp + 8192 + b0) = o;
    }
}

/* -------- Kernel 5: reduce 4 partials per pair; also column sums of Cv -------- */
__global__ __launch_bounds__(256)
void pair_finalize_kernel(const float* __restrict__ partials, float* __restrict__ pairacc) {
    int pair = blockIdx.x;
    __shared__ float buf[8256];
    for (int e = threadIdx.x; e < 8256; e += 256) {
        float s = 0.f;
        for (int c = 0; c < 4; ++c)
            s += partials[((size_t)(pair * 4 + c)) * 8256 + e];
        buf[e] = s;
        pairacc[(size_t)pair * 8320 + e] = s;
    }
    __syncthreads();
    if (threadIdx.x < 64) {
        float s = 0.f;
        for (int a = 0; a < 64; ++a) s += buf[4096 + a * 64 + threadIdx.x];
        pairacc[(size_t)pair * 8320 + 8256 + threadIdx.x] = s;
    }
}

/* -------- Kernel 6: Q-side row stats + two 64x64 matvecs + combine + split -------- */
__global__ __launch_bounds__(256)
void q_apply_kernel(const float* __restrict__ f, const float* __restrict__ pairacc,
                    const float* __restrict__ cov_raw, const float* __restrict__ var_raw,
                    ushort* __restrict__ Oh, ushort* __restrict__ Ol) {
    int bid = blockIdx.x;             /* pair*64 + nchunk */
    int pair = bid >> 6, nchunk = bid & 63;
    int hh = pair & 7, qg = pair >> 3;
    __shared__ float P_s[4096];
    __shared__ float C_s[4096];
    __shared__ float u_s[64], sc_s[64];
    const float* pa = pairacc + (size_t)pair * 8320;
    for (int e = threadIdx.x; e < 4096; e += 256) {
        P_s[e] = pa[e];
        C_s[e] = pa[4096 + e];
    }
    if (threadIdx.x < 64) {
        u_s[threadIdx.x]  = pa[8192 + threadIdx.x];
        sc_s[threadIdx.x] = pa[8256 + threadIdx.x];
    }
    __syncthreads();
    float cov_w = 1.0f / (1.0f + expf(-cov_raw[0]));
    float var_w = 1.0f / (1.0f + expf(-var_raw[0]));
    float cos_w = 1.0f - cov_w - var_w;
    float cw_cov = cov_w * (1.0f / 64.0f);
    float cw_var = var_w * (1.0f / 64.0f);
    int wave = threadIdx.x >> 6, lane = threadIdx.x & 63;
    const float* Fq = f + ((size_t)(qg * NTOK)) * D_MODEL + hh * HDIM;
    for (int r = 0; r < 8; ++r) {
        int n = nchunk * 32 + wave * 8 + r;
        float fq = Fq[(size_t)n * D_MODEL + lane];
        float s = fq, sq = fq * fq;
        for (int m = 1; m < 64; m <<= 1) {
            s  += __shfl_xor(s, m);
            sq += __shfl_xor(sq, m);
        }
        float qmean = s * (1.0f / 64.0f);
        float rqn   = 1.0f / sqrtf(sq);
        float qvar  = (sq - s * qmean) * (1.0f / 63.0f);
        float y1 = 0.f, y2 = 0.f;
#pragma unroll 8
        for (int a = 0; a < 64; ++a) {
            float vbc = __shfl(fq, a);
            y1 += vbc * P_s[a * 64 + lane];
            y2 += vbc * C_s[a * 64 + lane];
        }
        float res = cos_w * rqn * y1
                  + cw_cov * (y2 - qmean * sc_s[lane])
                  + cw_var * qvar * u_s[lane];
        ushort oh, ol;
        split2(res, oh, ol);
        size_t o = ((size_t)(qg * NTOK + n)) * D_MODEL + hh * HDIM + lane;
        Oh[o] = oh;
        Ol[o] = ol;
    }
}

extern "C" void kernel_launch(void* const* d_in, const int* in_sizes, int n_in,
                              void* d_out, int out_size, void* d_ws, size_t ws_size,
                              hipStream_t stream) {
    const float* q     = (const float*)d_in[0];
    const float* k     = (const float*)d_in[1];
    const float* v     = (const float*)d_in[2];
    const float* gamma = (const float*)d_in[3];
    const float* beta  = (const float*)d_in[4];
    const float* w_in  = (const float*)d_in[5];
    const float* w_out = (const float*)d_in[6];
    const float* b_out = (const float*)d_in[7];
    const float* cov_r = (const float*)d_in[8];
    const float* var_r = (const float*)d_in[9];
    float* out = (float*)d_out;

    /* workspace layout (74.5 MB; round-1 used 76.8 MB so ws_size covers it) */
    float*  ws       = (float*)d_ws;
    float*  f        = ws;                                   /* 3*8192*512 f32  = 50.33 MB */
    ushort* Ah       = (ushort*)(f + (size_t)3 * ROWS_PER_T * D_MODEL); /* 8192*512 u16 */
    ushort* Al       = Ah + (size_t)ROWS_PER_T * D_MODEL;
    ushort* Whi      = Al + (size_t)ROWS_PER_T * D_MODEL;    /* 512*512 u16 each */
    ushort* Wli      = Whi + D_MODEL * D_MODEL;
    ushort* Who      = Wli + D_MODEL * D_MODEL;
    ushort* Wlo      = Who + D_MODEL * D_MODEL;
    float*  partials = (float*)(Wlo + D_MODEL * D_MODEL);    /* 128*8256 f32 */
    float*  pairacc  = partials + (size_t)128 * 8256;        /* 32*8320 f32  */

    hipLaunchKernelGGL(split_mat_kernel, dim3(D_MODEL * D_MODEL / 2048), dim3(256), 0, stream,
                       w_in, Whi, Wli);
    hipLaunchKernelGGL(split_mat_kernel, dim3(D_MODEL * D_MODEL / 2048), dim3(256), 0, stream,
                       w_out, Who, Wlo);

    const float* srcs[3] = {q, k, v};
    for (int t = 0; t < 3; ++t) {
        hipLaunchKernelGGL(ln_split_kernel, dim3(ROWS_PER_T / 4), dim3(256), 0, stream,
                           srcs[t], gamma, beta, Ah, Al);
        hipLaunchKernelGGL((gemm_split_kernel<false>), dim3(ROWS_PER_T / 128, 4), dim3(256), 0, stream,
                           Ah, Al, Whi, Wli, (const float*)nullptr,
                           f + (size_t)t * ROWS_PER_T * D_MODEL);
    }

    hipLaunchKernelGGL(pair_reduce_kernel, dim3(128), dim3(256), 0, stream, f, partials);
    hipLaunchKernelGGL(pair_finalize_kernel, dim3(32), dim3(256), 0, stream, partials, pairacc);
    /* q_apply writes bf16 hi/lo of attn-out directly into Ah/Al (dead after ln gemms) */
    hipLaunchKernelGGL(q_apply_kernel, dim3(2048), dim3(256), 0, stream,
                       f, pairacc, cov_r, var_r, Ah, Al);
    hipLaunchKernelGGL((gemm_split_kernel<true>), dim3(ROWS_PER_T / 128, 4), dim3(256), 0, stream,
                       Ah, Al, Who, Wlo, b_out, out);
}

// Round 3
// 173.154 us; speedup vs baseline: 2.1825x; 1.4322x over previous
//
#include <hip/hip_runtime.h>
#include <hip/hip_bf16.h>
#include <math.h>

#define D_MODEL 512
#define NTOK 2048
#define QGRP 4
#define NHEAD 8
#define HDIM 64
#define ROWS_PER_T (QGRP * NTOK)          /* 8192 */
#define LN_EPS 1e-5f

typedef __attribute__((ext_vector_type(8))) short short8;
typedef __attribute__((ext_vector_type(8))) __bf16 bf16x8;
typedef __attribute__((ext_vector_type(4))) float f32x4;

__device__ inline void split2(float y, ushort& h, ushort& l) {
    __hip_bfloat16 hb = __float2bfloat16(y);
    float hf = __bfloat162float(hb);
    __hip_bfloat16 lb = __float2bfloat16(y - hf);
    h = *reinterpret_cast<ushort*>(&hb);
    l = *reinterpret_cast<ushort*>(&lb);
}

__device__ inline float b2f(ushort u) {
    unsigned int x = ((unsigned int)u) << 16;
    return __uint_as_float(x);
}

__device__ inline void split8v(const float4& p0, const float4& p1, bf16x8& bh, bf16x8& bl) {
    float xv[8] = {p0.x, p0.y, p0.z, p0.w, p1.x, p1.y, p1.z, p1.w};
    ushort hs[8], ls[8];
#pragma unroll
    for (int j = 0; j < 8; ++j) split2(xv[j], hs[j], ls[j]);
    bh = *(const bf16x8*)hs;
    bl = *(const bf16x8*)ls;
}

/* ------- Kernel 1: fused LayerNorm + bf16 hi/lo split:  A = LN(x)*gamma+beta ------- */
__global__ __launch_bounds__(256)
void ln_split_kernel(const float* __restrict__ x, const float* __restrict__ gamma,
                     const float* __restrict__ beta,
                     ushort* __restrict__ Ah, ushort* __restrict__ Al) {
    int wave = threadIdx.x >> 6, lane = threadIdx.x & 63;
    size_t row = (size_t)blockIdx.x * 4 + wave;
    const float* src = x + row * D_MODEL + lane * 8;
    float4 a = *(const float4*)src;
    float4 b = *(const float4*)(src + 4);
    float s  = a.x + a.y + a.z + a.w + b.x + b.y + b.z + b.w;
    float sq = a.x*a.x + a.y*a.y + a.z*a.z + a.w*a.w
             + b.x*b.x + b.y*b.y + b.z*b.z + b.w*b.w;
    for (int m = 1; m < 64; m <<= 1) {
        s  += __shfl_xor(s, m);
        sq += __shfl_xor(sq, m);
    }
    float mu   = s * (1.0f / (float)D_MODEL);
    float var  = sq * (1.0f / (float)D_MODEL) - mu * mu;
    float rstd = 1.0f / sqrtf(var + LN_EPS);
    float4 g0 = *(const float4*)(gamma + lane * 8);
    float4 g1 = *(const float4*)(gamma + lane * 8 + 4);
    float4 t0 = *(const float4*)(beta + lane * 8);
    float4 t1 = *(const float4*)(beta + lane * 8 + 4);
    float xv[8] = {a.x, a.y, a.z, a.w, b.x, b.y, b.z, b.w};
    float gv[8] = {g0.x, g0.y, g0.z, g0.w, g1.x, g1.y, g1.z, g1.w};
    float bv[8] = {t0.x, t0.y, t0.z, t0.w, t1.x, t1.y, t1.z, t1.w};
    ushort hs[8], ls[8];
#pragma unroll
    for (int j = 0; j < 8; ++j) {
        float y = (xv[j] - mu) * rstd * gv[j] + bv[j];
        split2(y, hs[j], ls[j]);
    }
    *(short8*)(Ah + row * D_MODEL + lane * 8) = *(const short8*)hs;
    *(short8*)(Al + row * D_MODEL + lane * 8) = *(const short8*)ls;
}

/* ------- Kernel 2: plain elementwise hi/lo split (for weights) ------- */
__global__ __launch_bounds__(256)
void split_mat_kernel(const float* __restrict__ W, ushort* __restrict__ Wh,
                      ushort* __restrict__ Wl) {
    size_t i = ((size_t)blockIdx.x * 256 + threadIdx.x) * 8;
    float4 a = *(const float4*)(W + i);
    float4 b = *(const float4*)(W + i + 4);
    float xv[8] = {a.x, a.y, a.z, a.w, b.x, b.y, b.z, b.w};
    ushort hs[8], ls[8];
#pragma unroll
    for (int j = 0; j < 8; ++j) split2(xv[j], hs[j], ls[j]);
    *(short8*)(Wh + i) = *(const short8*)hs;
    *(short8*)(Wl + i) = *(const short8*)ls;
}

/* ------- Kernel 3: split-bf16 MFMA GEMM  C = (Ah+Al)(Wh+Wl)^T
   MODE 0: fp32 C.  MODE 1: bf16 hi/lo split out (Ch,Cl).  MODE 2: fp32 C + bias.
   128x128 tile, BK=64, 4 waves (2x2), 16x16x32 MFMA, 3 products (hh, hl, lh). ------- */
template <int MODE>
__global__ __launch_bounds__(256, 2)
void gemm_split_kernel(const ushort* __restrict__ Ah, const ushort* __restrict__ Al,
                       const ushort* __restrict__ Wh, const ushort* __restrict__ Wl,
                       const float* __restrict__ bias, float* __restrict__ C,
                       ushort* __restrict__ Ch, ushort* __restrict__ Cl) {
    __shared__ __align__(16) ushort sA[2][128][64];
    __shared__ __align__(16) ushort sW[2][128][64];
    int tid  = threadIdx.x;
    int lane = tid & 63, wid = tid >> 6;
    int wr = wid >> 1, wc = wid & 1;
    size_t rowBase = (size_t)blockIdx.x * 128;
    size_t colBase = (size_t)blockIdx.y * 128;
    const ushort* gA[2] = {Ah, Al};
    const ushort* gW[2] = {Wh, Wl};

    int sr = tid >> 3;            /* staging row stepped by 32 per pass   */
    int sc8 = tid & 7;            /* staging 8-elem column granule        */

    short8 st[16];

#define LOADK(KT)                                                                  \
    {                                                                              \
        int idx = 0;                                                               \
        _Pragma("unroll")                                                          \
        for (int hl = 0; hl < 2; ++hl)                                             \
            _Pragma("unroll")                                                      \
            for (int p = 0; p < 4; ++p) {                                          \
                int r = p * 32 + sr;                                               \
                st[idx++] = *(const short8*)(gA[hl] + (rowBase + r) * D_MODEL +    \
                                             (KT) + sc8 * 8);                      \
            }                                                                      \
        _Pragma("unroll")                                                          \
        for (int hl = 0; hl < 2; ++hl)                                             \
            _Pragma("unroll")                                                      \
            for (int p = 0; p < 4; ++p) {                                          \
                int r = p * 32 + sr;                                               \
                st[idx++] = *(const short8*)(gW[hl] + (colBase + r) * D_MODEL +    \
                                             (KT) + sc8 * 8);                      \
            }                                                                      \
    }

    f32x4 acc[4][4] = {};

    LOADK(0);
    for (int step = 0; step < 8; ++step) {
        __syncthreads();
        {   /* write staged regs to LDS, swizzled */
            int idx = 0;
#pragma unroll
            for (int hl = 0; hl < 2; ++hl)
#pragma unroll
                for (int p = 0; p < 4; ++p) {
                    int r = p * 32 + sr;
                    *(short8*)&sA[hl][r][((sc8 ^ (r & 7)) << 3)] = st[idx++];
                }
#pragma unroll
            for (int hl = 0; hl < 2; ++hl)
#pragma unroll
                for (int p = 0; p < 4; ++p) {
                    int r = p * 32 + sr;
                    *(short8*)&sW[hl][r][((sc8 ^ (r & 7)) << 3)] = st[idx++];
                }
        }
        __syncthreads();
        if (step < 7) LOADK((step + 1) * 64);
#pragma unroll
        for (int sl = 0; sl < 2; ++sl) {
            bf16x8 aH[4], aL[4];
#pragma unroll
            for (int m = 0; m < 4; ++m) {
                int r = wr * 64 + m * 16 + (lane & 15);
                int cs = ((sl * 4 + (lane >> 4)) ^ (r & 7)) << 3;
                aH[m] = *(const bf16x8*)&sA[0][r][cs];
                aL[m] = *(const bf16x8*)&sA[1][r][cs];
            }
#pragma unroll
            for (int n = 0; n < 4; ++n) {
                int r = wc * 64 + n * 16 + (lane & 15);
                int cs = ((sl * 4 + (lane >> 4)) ^ (r & 7)) << 3;
                bf16x8 bH = *(const bf16x8*)&sW[0][r][cs];
                bf16x8 bL = *(const bf16x8*)&sW[1][r][cs];
#pragma unroll
                for (int m = 0; m < 4; ++m) {
                    acc[m][n] = __builtin_amdgcn_mfma_f32_16x16x32_bf16(aL[m], bH, acc[m][n], 0, 0, 0);
                    acc[m][n] = __builtin_amdgcn_mfma_f32_16x16x32_bf16(aH[m], bL, acc[m][n], 0, 0, 0);
                    acc[m][n] = __builtin_amdgcn_mfma_f32_16x16x32_bf16(aH[m], bH, acc[m][n], 0, 0, 0);
                }
            }
        }
    }
#pragma unroll
    for (int m = 0; m < 4; ++m)
#pragma unroll
        for (int n = 0; n < 4; ++n) {
            size_t col = colBase + wc * 64 + n * 16 + (lane & 15);
            size_t rb  = rowBase + wr * 64 + m * 16 + ((lane >> 4) << 2);
            if (MODE == 1) {
#pragma unroll
                for (int r = 0; r < 4; ++r) {
                    ushort oh, ol;
                    split2(acc[m][n][r], oh, ol);
                    Ch[(rb + r) * D_MODEL + col] = oh;
                    Cl[(rb + r) * D_MODEL + col] = ol;
                }
            } else {
                float bv = (MODE == 2) ? bias[col] : 0.0f;
#pragma unroll
                for (int r = 0; r < 4; ++r)
                    C[(rb + r) * D_MODEL + col] = acc[m][n][r] + bv;
            }
        }
#undef LOADK
}

/* ------- Kernel 4: per-(head,group) K-side reductions (4 chunks, no atomics) ------- */
__global__ __launch_bounds__(256)
void pair_reduce_kernel(const float* __restrict__ fk, const float* __restrict__ fv,
                        float* __restrict__ partials) {
    int pc = blockIdx.x;              /* pair*4 + chunk */
    int pair = pc >> 2, chunk = pc & 3;
    int h = pair & 7, qg = pair >> 3;
    const float* Fk = fk + ((size_t)(qg * NTOK)) * D_MODEL + h * HDIM;
    const float* Fv = fv + ((size_t)(qg * NTOK)) * D_MODEL + h * HDIM;
    __shared__ float fk_s[64][64];
    __shared__ float fv_s[64][64];
    __shared__ float rkn_s[64], kvar_s[64];
    int tid = threadIdx.x;
    int a0 = (tid >> 4) << 2, b0 = (tid & 15) << 2;
    int lr = tid >> 4;
    int lc = (tid & 15) << 2;
    float accP[4][4] = {{0.f}}, accC[4][4] = {{0.f}};
    float uv[4] = {0.f, 0.f, 0.f, 0.f};
    for (int t = 0; t < 8; ++t) {
        int rowbase = chunk * 512 + t * 64;
        float4 vk[4], vv[4];
#pragma unroll
        for (int j = 0; j < 4; ++j) {
            size_t n = (size_t)(rowbase + lr + 16 * j);
            vk[j] = *(const float4*)(Fk + n * D_MODEL + lc);
            vv[j] = *(const float4*)(Fv + n * D_MODEL + lc);
        }
        __syncthreads();
#pragma unroll
        for (int j = 0; j < 4; ++j) {
            int m = lr + 16 * j;
            *(float4*)&fk_s[m][lc] = vk[j];
            *(float4*)&fv_s[m][lc] = vv[j];
        }
#pragma unroll
        for (int j = 0; j < 4; ++j) {
            float s  = vk[j].x + vk[j].y + vk[j].z + vk[j].w;
            float sq = vk[j].x*vk[j].x + vk[j].y*vk[j].y + vk[j].z*vk[j].z + vk[j].w*vk[j].w;
            for (int msk = 1; msk < 16; msk <<= 1) {
                s  += __shfl_xor(s,  msk);
                sq += __shfl_xor(sq, msk);
            }
            if ((tid & 15) == 0) {
                int m = lr + 16 * j;
                rkn_s[m]  = 1.0f / sqrtf(sq);
                kvar_s[m] = (sq - s * s * (1.0f / 64.0f)) * (1.0f / 63.0f);
            }
        }
        __syncthreads();
#pragma unroll
        for (int m = 0; m < 64; ++m) {
            float4 fk4 = *(const float4*)&fk_s[m][a0];
            float4 fv4 = *(const float4*)&fv_s[m][b0];
            float rkn = rkn_s[m];
            float fkn[4] = {fk4.x*rkn, fk4.y*rkn, fk4.z*rkn, fk4.w*rkn};
            float fkr[4] = {fk4.x, fk4.y, fk4.z, fk4.w};
            float fvr[4] = {fv4.x, fv4.y, fv4.z, fv4.w};
#pragma unroll
            for (int i = 0; i < 4; ++i)
#pragma unroll
                for (int jj = 0; jj < 4; ++jj) {
                    accP[i][jj] += fkn[i] * fvr[jj];
                    accC[i][jj] += fkr[i] * fvr[jj];
                }
            if ((tid >> 4) == 0) {
                float kv = kvar_s[m];
#pragma unroll
                for (int jj = 0; jj < 4; ++jj) uv[jj] += kv * fvr[jj];
            }
        }
    }
    float* outp = partials + (size_t)pc * 8256;
#pragma unroll
    for (int i = 0; i < 4; ++i) {
        float4 o1, o2;
        o1.x = accP[i][0]; o1.y = accP[i][1]; o1.z = accP[i][2]; o1.w = accP[i][3];
        o2.x = accC[i][0]; o2.y = accC[i][1]; o2.z = accC[i][2]; o2.w = accC[i][3];
        *(float4*)(outp + (a0 + i) * 64 + b0)        = o1;
        *(float4*)(outp + 4096 + (a0 + i) * 64 + b0) = o2;
    }
    if ((tid >> 4) == 0) {
        float4 o;
        o.x = uv[0]; o.y = uv[1]; o.z = uv[2]; o.w = uv[3];
        *(float4*)(outp + 8192 + b0) = o;
    }
}

/* -------- Kernel 5: reduce 4 partials per pair; also column sums of Cv -------- */
__global__ __launch_bounds__(256)
void pair_finalize_kernel(const float* __restrict__ partials, float* __restrict__ pairacc) {
    int pair = blockIdx.x;
    __shared__ float buf[8256];
    for (int e = threadIdx.x; e < 8256; e += 256) {
        float s = 0.f;
        for (int c = 0; c < 4; ++c)
            s += partials[((size_t)(pair * 4 + c)) * 8256 + e];
        buf[e] = s;
        pairacc[(size_t)pair * 8320 + e] = s;
    }
    __syncthreads();
    if (threadIdx.x < 64) {
        float s = 0.f;
        for (int a = 0; a < 64; ++a) s += buf[4096 + a * 64 + threadIdx.x];
        pairacc[(size_t)pair * 8320 + 8256 + threadIdx.x] = s;
    }
}

/* -------- Kernel 6: Q-side apply via MFMA.
   Per pair: Y1 = Fq*P, Y2 = Fq*C (split-bf16, 3 products), row stats from
   fragment elements + 2 shfl_xor, rank-1 terms in epilogue, split out. -------- */
__global__ __launch_bounds__(256)
void q_apply_mfma_kernel(const ushort* __restrict__ Fqh, const ushort* __restrict__ Fql,
                         const float* __restrict__ pairacc,
                         const float* __restrict__ cov_raw, const float* __restrict__ var_raw,
                         ushort* __restrict__ Oh, ushort* __restrict__ Ol) {
    int pair = blockIdx.x >> 4, chunk = blockIdx.x & 15;
    int h = pair & 7, qg = pair >> 3;
    __shared__ float PT[64][68];   /* PT[c][a] = P[a][c], pad 4: 2-way banks only */
    __shared__ float CT[64][68];
    const float* pa = pairacc + (size_t)pair * 8320;
    for (int e = threadIdx.x; e < 4096; e += 256) {
        int a = e >> 6, c = e & 63;
        PT[c][a] = pa[e];
        CT[c][a] = pa[4096 + e];
    }
    __syncthreads();
    int tid = threadIdx.x, lane = tid & 63, wave = tid >> 6;
    size_t row0 = (size_t)qg * NTOK + (size_t)chunk * 128 + wave * 32;
    const ushort* qhp = Fqh + row0 * D_MODEL + h * HDIM;
    const ushort* qlp = Fql + row0 * D_MODEL + h * HDIM;

    bf16x8 aH[2][2], aL[2][2];
    float qsum[2], qsq[2];
#pragma unroll
    for (int m = 0; m < 2; ++m) {
        int r = m * 16 + (lane & 15);
        int k0 = (lane >> 4) * 8;
        float s = 0.f, sq = 0.f;
#pragma unroll
        for (int ks = 0; ks < 2; ++ks) {
            short8 hv = *(const short8*)(qhp + (size_t)r * D_MODEL + ks * 32 + k0);
            short8 lv = *(const short8*)(qlp + (size_t)r * D_MODEL + ks * 32 + k0);
            aH[m][ks] = *(const bf16x8*)&hv;
            aL[m][ks] = *(const bf16x8*)&lv;
#pragma unroll
            for (int j = 0; j < 8; ++j) {
                float val = b2f((ushort)hv[j]) + b2f((ushort)lv[j]);
                s += val; sq += val * val;
            }
        }
        s  += __shfl_xor(s, 16);  s  += __shfl_xor(s, 32);
        sq += __shfl_xor(sq, 16); sq += __shfl_xor(sq, 32);
        qsum[m] = s; qsq[m] = sq;
    }

    f32x4 accP[2][4] = {}, accC[2][4] = {};
#pragma unroll
    for (int n = 0; n < 4; ++n) {
        int c = n * 16 + (lane & 15);
#pragma unroll
        for (int ks = 0; ks < 2; ++ks) {
            int kb = ks * 32 + (lane >> 4) * 8;
            {
                float4 p0 = *(const float4*)&PT[c][kb];
                float4 p1 = *(const float4*)&PT[c][kb + 4];
                bf16x8 bH, bL;
                split8v(p0, p1, bH, bL);
#pragma unroll
                for (int m = 0; m < 2; ++m) {
                    accP[m][n] = __builtin_amdgcn_mfma_f32_16x16x32_bf16(aL[m][ks], bH, accP[m][n], 0, 0, 0);
                    accP[m][n] = __builtin_amdgcn_mfma_f32_16x16x32_bf16(aH[m][ks], bL, accP[m][n], 0, 0, 0);
                    accP[m][n] = __builtin_amdgcn_mfma_f32_16x16x32_bf16(aH[m][ks], bH, accP[m][n], 0, 0, 0);
                }
            }
            {
                float4 p0 = *(const float4*)&CT[c][kb];
                float4 p1 = *(const float4*)&CT[c][kb + 4];
                bf16x8 bH, bL;
                split8v(p0, p1, bH, bL);
#pragma unroll
                for (int m = 0; m < 2; ++m) {
                    accC[m][n] = __builtin_amdgcn_mfma_f32_16x16x32_bf16(aL[m][ks], bH, accC[m][n], 0, 0, 0);
                    accC[m][n] = __builtin_amdgcn_mfma_f32_16x16x32_bf16(aH[m][ks], bL, accC[m][n], 0, 0, 0);
                    accC[m][n] = __builtin_amdgcn_mfma_f32_16x16x32_bf16(aH[m][ks], bH, accC[m][n], 0, 0, 0);
                }
            }
        }
    }

    float cw = 1.0f / (1.0f + expf(-cov_raw[0]));
    float vw = 1.0f / (1.0f + expf(-var_raw[0]));
    float cos_w = 1.0f - cw - vw;
    float cw_cov = cw * (1.0f / 64.0f);
    float cw_var = vw * (1.0f / 64.0f);
#pragma unroll
    for (int n = 0; n < 4; ++n) {
        int c = n * 16 + (lane & 15);
        float u_c  = pa[8192 + c];
        float sc_c = pa[8256 + c];
#pragma unroll
        for (int m = 0; m < 2; ++m)
#pragma unroll
            for (int i = 0; i < 4; ++i) {
                int rp = ((lane >> 4) << 2) + i;
                float s  = __shfl(qsum[m], rp);
                float sq = __shfl(qsq[m], rp);
                float qmean = s * (1.0f / 64.0f);
                float rqn   = 1.0f / sqrtf(sq);
                float qvar  = (sq - s * qmean) * (1.0f / 63.0f);
                float res = cos_w * rqn * accP[m][n][i]
                          + cw_cov * (accC[m][n][i] - qmean * sc_c)
                          + cw_var * qvar * u_c;
                ushort oh, ol;
                split2(res, oh, ol);
                size_t o = (row0 + m * 16 + rp) * D_MODEL + h * HDIM + c;
                Oh[o] = oh;
                Ol[o] = ol;
            }
    }
}

extern "C" void kernel_launch(void* const* d_in, const int* in_sizes, int n_in,
                              void* d_out, int out_size, void* d_ws, size_t ws_size,
                              hipStream_t stream) {
    const float* q     = (const float*)d_in[0];
    const float* k     = (const float*)d_in[1];
    const float* v     = (const float*)d_in[2];
    const float* gamma = (const float*)d_in[3];
    const float* beta  = (const float*)d_in[4];
    const float* w_in  = (const float*)d_in[5];
    const float* w_out = (const float*)d_in[6];
    const float* b_out = (const float*)d_in[7];
    const float* cov_r = (const float*)d_in[8];
    const float* var_r = (const float*)d_in[9];
    float* out = (float*)d_out;

    /* workspace layout (~74.5 MB, same footprint as round 2) */
    float*  ws       = (float*)d_ws;
    float*  fk       = ws;                                    /* 8192*512 f32 */
    float*  fv       = fk + (size_t)ROWS_PER_T * D_MODEL;     /* 8192*512 f32 */
    ushort* Ah       = (ushort*)(fv + (size_t)ROWS_PER_T * D_MODEL);
    ushort* Al       = Ah + (size_t)ROWS_PER_T * D_MODEL;
    ushort* Fqh      = Al + (size_t)ROWS_PER_T * D_MODEL;
    ushort* Fql      = Fqh + (size_t)ROWS_PER_T * D_MODEL;
    ushort* Whi      = Fql + (size_t)ROWS_PER_T * D_MODEL;    /* 512*512 u16 each */
    ushort* Wli      = Whi + D_MODEL * D_MODEL;
    ushort* Who      = Wli + D_MODEL * D_MODEL;
    ushort* Wlo      = Who + D_MODEL * D_MODEL;
    float*  partials = (float*)(Wlo + D_MODEL * D_MODEL);     /* 128*8256 f32 */
    float*  pairacc  = partials + (size_t)128 * 8256;         /* 32*8320 f32  */

    hipLaunchKernelGGL(split_mat_kernel, dim3(D_MODEL * D_MODEL / 2048), dim3(256), 0, stream,
                       w_in, Whi, Wli);
    hipLaunchKernelGGL(split_mat_kernel, dim3(D_MODEL * D_MODEL / 2048), dim3(256), 0, stream,
                       w_out, Who, Wlo);

    /* q: LN -> split-GEMM -> bf16 hi/lo (Fqh/Fql) */
    hipLaunchKernelGGL(ln_split_kernel, dim3(ROWS_PER_T / 4), dim3(256), 0, stream,
                       q, gamma, beta, Ah, Al);
    hipLaunchKernelGGL((gemm_split_kernel<1>), dim3(ROWS_PER_T / 128, 4), dim3(256), 0, stream,
                       Ah, Al, Whi, Wli, (const float*)nullptr, (float*)nullptr, Fqh, Fql);
    /* k: LN -> split-GEMM -> fp32 fk */
    hipLaunchKernelGGL(ln_split_kernel, dim3(ROWS_PER_T / 4), dim3(256), 0, stream,
                       k, gamma, beta, Ah, Al);
    hipLaunchKernelGGL((gemm_split_kernel<0>), dim3(ROWS_PER_T / 128, 4), dim3(256), 0, stream,
                       Ah, Al, Whi, Wli, (const float*)nullptr, fk, (ushort*)nullptr, (ushort*)nullptr);
    /* v: LN -> split-GEMM -> fp32 fv */
    hipLaunchKernelGGL(ln_split_kernel, dim3(ROWS_PER_T / 4), dim3(256), 0, stream,
                       v, gamma, beta, Ah, Al);
    hipLaunchKernelGGL((gemm_split_kernel<0>), dim3(ROWS_PER_T / 128, 4), dim3(256), 0, stream,
                       Ah, Al, Whi, Wli, (const float*)nullptr, fv, (ushort*)nullptr, (ushort*)nullptr);

    hipLaunchKernelGGL(pair_reduce_kernel, dim3(128), dim3(256), 0, stream, fk, fv, partials);
    hipLaunchKernelGGL(pair_finalize_kernel, dim3(32), dim3(256), 0, stream, partials, pairacc);
    /* q_apply writes bf16 hi/lo of attn-out into Ah/Al (dead after ln gemms) */
    hipLaunchKernelGGL(q_apply_mfma_kernel, dim3(512), dim3(256), 0, stream,
                       Fqh, Fql, pairacc, cov_r, var_r, Ah, Al);
    hipLaunchKernelGGL((gemm_split_kernel<2>), dim3(ROWS_PER_T / 128, 4), dim3(256), 0, stream,
                       Ah, Al, Who, Wlo, b_out, out, (ushort*)nullptr, (ushort*)nullptr);
}